// Round 2
// baseline (242.105 us; speedup 1.0000x reference)
//
#include <hip/hip_runtime.h>
#include <math.h>

// IlluminationModel fused pipeline for MI355X (gfx950), f32 throughout.
// B=16384, N=1024, K=64. Output: zncc (B*N) then pred_depths (B), f32.
//
// ws layout (floats) — total 69632 floats = 272.5 KB:
//   [0,1024)        irf_rolled (normalized, rolled gaussian)
//   [1024,2048)     x = relu(learnable)
//   [2048,3072)     irf_input (circular conv)
//   [3072]          S = sum(irf_input)
//   [4096,69632)    corr_norm [k=64][n=1024]

#define NT 1024
#define RB 8   // rows per block in fused kernel

__global__ __launch_bounds__(1024) void irf_init(const float* __restrict__ learn,
                                                 float* __restrict__ irf_rolled,
                                                 float* __restrict__ xbuf) {
  __shared__ float red[NT];
  int t = threadIdx.x;
  float d = ((float)t - 511.0f) / 10.0f;           // mu=(N-1)//2=511, sigma=10
  float g = expf(-0.5f * d * d);
  red[t] = g;
  __syncthreads();
  for (int s = 512; s > 0; s >>= 1) {
    if (t < s) red[t] += red[t + s];
    __syncthreads();
  }
  float gsum = red[0];
  // roll by -mu: irf_rolled[(t-511) % N] = g_norm[t]
  irf_rolled[(t - 511) & (NT - 1)] = g / gsum;
  xbuf[t] = fmaxf(learn[t], 0.0f);
}

// circular conv: irf_input[t] = sum_d irf_rolled[d]*x[t-d]; gaussian support
// truncated to |d|<=96 (dropped terms < e^-46, far below f32 epsilon).
__global__ __launch_bounds__(256) void conv_init(const float* __restrict__ irf_rolled,
                                                 const float* __restrict__ xbuf,
                                                 float* __restrict__ irf_input) {
  __shared__ float irf_s[NT];
  __shared__ float x_s[NT];
  int tid = threadIdx.x;
  int t = blockIdx.x * 256 + tid;
  for (int i = tid; i < NT; i += 256) { irf_s[i] = irf_rolled[i]; x_s[i] = xbuf[i]; }
  __syncthreads();
  float acc = 0.0f;
  for (int d = -96; d <= 96; ++d)
    acc += irf_s[d & (NT - 1)] * x_s[(t - d) & (NT - 1)];
  irf_input[t] = acc;
}

__global__ __launch_bounds__(1024) void sum_init(const float* __restrict__ irf_input,
                                                 float* __restrict__ S) {
  __shared__ float red[NT];
  int t = threadIdx.x;
  red[t] = irf_input[t];
  __syncthreads();
  for (int s = 512; s > 0; s >>= 1) {
    if (t < s) red[t] += red[t + s];
    __syncthreads();
  }
  if (t == 0) S[0] = red[0];
}

// corr_norm[k][n]: zero-mean over k (64), divide by (L2 norm + 1e-8). One wave per column.
__global__ __launch_bounds__(256) void corr_init(const float* __restrict__ cmat,
                                                 float* __restrict__ corr) {
  int lane = threadIdx.x & 63;
  int wv = threadIdx.x >> 6;
  int n = blockIdx.x * 4 + wv;
  float w = cmat[lane * NT + n];
  float s = w;
#pragma unroll
  for (int off = 32; off > 0; off >>= 1) s += __shfl_xor(s, off);
  float mean = s * (1.0f / 64.0f);
  float d = w - mean;
  float q = d * d;
#pragma unroll
  for (int off = 32; off > 0; off >>= 1) q += __shfl_xor(q, off);
  corr[lane * NT + n] = d / (sqrtf(q) + 1e-8f);
}

// Fused main kernel: per block, RB=8 batch rows.
//  Phase B: build noisy rows in LDS (noisy never touches HBM).
//  Phase C: out[r][k] = sum_c cmat[k][c]*noisy[r][c]; zero-norm over k -> in_s (LDS).
//  Phase D: zncc[r][n] = sum_k in_s[r][k]*corr[k][n]; write zncc; fused
//           softmax(100*zncc) -> pred depth (zncc tile stays in registers).
__global__ __launch_bounds__(256) void fused_main(const int* __restrict__ bins,
                                                  const float* __restrict__ photon,
                                                  const float* __restrict__ sbrs,
                                                  const float* __restrict__ noise,
                                                  const float* __restrict__ cmat,
                                                  const float* __restrict__ irf_input,
                                                  const float* __restrict__ Sp,
                                                  const float* __restrict__ corr,
                                                  float* __restrict__ zncc,
                                                  float* __restrict__ pred) {
  __shared__ float irf_s[NT];
  __shared__ float noisy_s[RB][NT];
  __shared__ float part[64][33];  // [k][cq*8 + r], +1 padding breaks bank conflicts
  __shared__ float in_s[RB][64];
  __shared__ float redm[4][RB];
  __shared__ float rede[4][RB];
  __shared__ float redn[4][RB];

  int tid = threadIdx.x;
  for (int i = tid; i < NT; i += 256) irf_s[i] = irf_input[i];
  __syncthreads();
  float S = Sp[0];
  long b0 = (long)blockIdx.x * RB;
  int c0 = tid * 4;

  // ---- Phase B: noisy rows ----
#pragma unroll 1
  for (int r = 0; r < RB; ++r) {
    long b = b0 + r;
    int shift = bins[b] & (NT - 1);
    float ph = photon[b];
    float scal = ph / S;
    float amb = ph / sbrs[b] * (1.0f / 1024.0f);
    float4 nz = *reinterpret_cast<const float4*>(noise + b * NT + c0);
    float4 sc, o;
    sc.x = irf_s[(c0 + 0 - shift) & (NT - 1)] * scal + amb;
    sc.y = irf_s[(c0 + 1 - shift) & (NT - 1)] * scal + amb;
    sc.z = irf_s[(c0 + 2 - shift) & (NT - 1)] * scal + amb;
    sc.w = irf_s[(c0 + 3 - shift) & (NT - 1)] * scal + amb;
    o.x = sc.x + sqrtf(sc.x) * nz.x;
    o.y = sc.y + sqrtf(sc.y) * nz.y;
    o.z = sc.z + sqrtf(sc.z) * nz.z;
    o.w = sc.w + sqrtf(sc.w) * nz.w;
    *reinterpret_cast<float4*>(&noisy_s[r][c0]) = o;
  }
  __syncthreads();

  // ---- Phase C: GEMM1 (k-half per wave parity, c-quarter per lane-half) ----
  int lane = tid & 63, wv = tid >> 6;
  int k = ((wv & 1) << 5) | (lane & 31);
  int cq = ((wv >> 1) << 1) | (lane >> 5);
  const float* crow = cmat + (size_t)k * NT + cq * 256;
  {
    float acc[RB];
#pragma unroll
    for (int r = 0; r < RB; ++r) acc[r] = 0.0f;
#pragma unroll 2
    for (int cc = 0; cc < 256; cc += 4) {
      float4 w4 = *reinterpret_cast<const float4*>(crow + cc);
#pragma unroll
      for (int r = 0; r < RB; ++r) {
        float4 n4 = *reinterpret_cast<const float4*>(&noisy_s[r][cq * 256 + cc]);
        acc[r] = fmaf(w4.w, n4.w, fmaf(w4.z, n4.z, fmaf(w4.y, n4.y, fmaf(w4.x, n4.x, acc[r]))));
      }
    }
#pragma unroll
    for (int r = 0; r < RB; ++r) part[k][cq * 8 + r] = acc[r];
  }
  __syncthreads();
  // combine c-quarters + zero-norm over k. Wave wv handles rows 2wv, 2wv+1; lane = k.
#pragma unroll
  for (int rr = 0; rr < 2; ++rr) {
    int r = wv * 2 + rr;
    float v = part[lane][0 * 8 + r] + part[lane][1 * 8 + r] +
              part[lane][2 * 8 + r] + part[lane][3 * 8 + r];
    float s = v;
#pragma unroll
    for (int off = 32; off > 0; off >>= 1) s += __shfl_xor(s, off);
    float mean = s * (1.0f / 64.0f);
    float d = v - mean;
    float q = d * d;
#pragma unroll
    for (int off = 32; off > 0; off >>= 1) q += __shfl_xor(q, off);
    in_s[r][lane] = d / (sqrtf(q) + 1e-8f);
  }
  __syncthreads();

  // ---- Phase D: GEMM2 + zncc write + fused softmax/pred ----
  int n0 = tid * 4;
  float acc[RB][4];
#pragma unroll
  for (int r = 0; r < RB; ++r)
#pragma unroll
    for (int j = 0; j < 4; ++j) acc[r][j] = 0.0f;

  for (int k4 = 0; k4 < 64; k4 += 4) {
    float4 cv0 = *reinterpret_cast<const float4*>(corr + (size_t)(k4 + 0) * NT + n0);
    float4 cv1 = *reinterpret_cast<const float4*>(corr + (size_t)(k4 + 1) * NT + n0);
    float4 cv2 = *reinterpret_cast<const float4*>(corr + (size_t)(k4 + 2) * NT + n0);
    float4 cv3 = *reinterpret_cast<const float4*>(corr + (size_t)(k4 + 3) * NT + n0);
#pragma unroll
    for (int r = 0; r < RB; ++r) {
      float4 iv = *reinterpret_cast<const float4*>(&in_s[r][k4]);
      acc[r][0] = fmaf(iv.x, cv0.x, fmaf(iv.y, cv1.x, fmaf(iv.z, cv2.x, fmaf(iv.w, cv3.x, acc[r][0]))));
      acc[r][1] = fmaf(iv.x, cv0.y, fmaf(iv.y, cv1.y, fmaf(iv.z, cv2.y, fmaf(iv.w, cv3.y, acc[r][1]))));
      acc[r][2] = fmaf(iv.x, cv0.z, fmaf(iv.y, cv1.z, fmaf(iv.z, cv2.z, fmaf(iv.w, cv3.z, acc[r][2]))));
      acc[r][3] = fmaf(iv.x, cv0.w, fmaf(iv.y, cv1.w, fmaf(iv.z, cv2.w, fmaf(iv.w, cv3.w, acc[r][3]))));
    }
  }

#pragma unroll
  for (int r = 0; r < RB; ++r) {
    float4 z;
    z.x = acc[r][0]; z.y = acc[r][1]; z.z = acc[r][2]; z.w = acc[r][3];
    *reinterpret_cast<float4*>(zncc + (b0 + r) * NT + n0) = z;
  }

  // per-row max
#pragma unroll
  for (int r = 0; r < RB; ++r) {
    float m = fmaxf(fmaxf(acc[r][0], acc[r][1]), fmaxf(acc[r][2], acc[r][3]));
#pragma unroll
    for (int off = 32; off > 0; off >>= 1) m = fmaxf(m, __shfl_xor(m, off));
    if (lane == 0) redm[wv][r] = m;
  }
  __syncthreads();
  float rmax[RB];
#pragma unroll
  for (int r = 0; r < RB; ++r)
    rmax[r] = fmaxf(fmaxf(redm[0][r], redm[1][r]), fmaxf(redm[2][r], redm[3][r]));
  // exp sums + index-weighted sums
#pragma unroll
  for (int r = 0; r < RB; ++r) {
    float e0 = expf(100.0f * (acc[r][0] - rmax[r]));
    float e1 = expf(100.0f * (acc[r][1] - rmax[r]));
    float e2 = expf(100.0f * (acc[r][2] - rmax[r]));
    float e3 = expf(100.0f * (acc[r][3] - rmax[r]));
    float es = e0 + e1 + e2 + e3;
    float ns = e0 * (float)(n0 + 0) + e1 * (float)(n0 + 1) +
               e2 * (float)(n0 + 2) + e3 * (float)(n0 + 3);
#pragma unroll
    for (int off = 32; off > 0; off >>= 1) {
      es += __shfl_xor(es, off);
      ns += __shfl_xor(ns, off);
    }
    if (lane == 0) { rede[wv][r] = es; redn[wv][r] = ns; }
  }
  __syncthreads();
  if (tid < RB) {
    int r = tid;
    float es = rede[0][r] + rede[1][r] + rede[2][r] + rede[3][r];
    float ns = redn[0][r] + redn[1][r] + redn[2][r] + redn[3][r];
    pred[b0 + r] = ns / es;
  }
}

extern "C" void kernel_launch(void* const* d_in, const int* in_sizes, int n_in,
                              void* d_out, int out_size, void* d_ws, size_t ws_size,
                              hipStream_t stream) {
  const int*   bins   = (const int*)d_in[0];
  const float* photon = (const float*)d_in[1];
  const float* sbrs   = (const float*)d_in[2];
  const float* learn  = (const float*)d_in[3];
  const float* cmat   = (const float*)d_in[4];
  const float* noise  = (const float*)d_in[5];
  float* out = (float*)d_out;
  float* ws = (float*)d_ws;

  float* irf_rolled = ws;               // 1024
  float* xbuf       = ws + 1024;        // 1024
  float* irf_input  = ws + 2048;        // 1024
  float* Sslot      = ws + 3072;        // 1
  float* corr       = ws + 4096;        // 64*1024

  int B = in_sizes[0];
  float* pred = out + (size_t)B * NT;

  hipLaunchKernelGGL(irf_init, dim3(1), dim3(1024), 0, stream, learn, irf_rolled, xbuf);
  hipLaunchKernelGGL(conv_init, dim3(4), dim3(256), 0, stream, irf_rolled, xbuf, irf_input);
  hipLaunchKernelGGL(sum_init, dim3(1), dim3(1024), 0, stream, irf_input, Sslot);
  hipLaunchKernelGGL(corr_init, dim3(256), dim3(256), 0, stream, cmat, corr);
  hipLaunchKernelGGL(fused_main, dim3(B / RB), dim3(256), 0, stream,
                     bins, photon, sbrs, noise, cmat, irf_input, Sslot, corr, out, pred);
}

// Round 4
// 238.696 us; speedup vs baseline: 1.0143x; 1.0143x over previous
//
#include <hip/hip_runtime.h>
#include <math.h>

// IlluminationModel fused pipeline for MI355X (gfx950), f32 throughout.
// B=16384, N=1024, K=64. Output: zncc (B*N) then pred_depths (B), f32.
//
// ws layout (floats):
//   [2048,3072)     irf_input (circular conv)
//   [3072]          S = sum(irf_input)
//   [4096,69632)    corr_norm [k=64][n=1024]

#define NT 1024
#define RB 8   // rows per block in fused kernel

// Single-block prelude: gaussian IRF -> normalize/roll -> relu(x) -> circular
// conv (support truncated to |d|<=96; dropped terms < e^-46) -> sum S.
__global__ __launch_bounds__(1024) void prelude(const float* __restrict__ learn,
                                                float* __restrict__ irf_input,
                                                float* __restrict__ S) {
  __shared__ float red[NT];
  __shared__ float irf_l[NT];
  __shared__ float x_l[NT];
  int t = threadIdx.x;
  float d = ((float)t - 511.0f) / 10.0f;           // mu=(N-1)//2=511, sigma=10
  float g = expf(-0.5f * d * d);
  red[t] = g;
  __syncthreads();
  for (int s = 512; s > 0; s >>= 1) {
    if (t < s) red[t] += red[t + s];
    __syncthreads();
  }
  float gsum = red[0];
  // roll by -mu: irf_l[(t-511) % N] = g_norm[t]
  irf_l[(t - 511) & (NT - 1)] = g / gsum;
  x_l[t] = fmaxf(learn[t], 0.0f);
  __syncthreads();
  float acc = 0.0f;
  for (int dd = -96; dd <= 96; ++dd)
    acc += irf_l[dd & (NT - 1)] * x_l[(t - dd) & (NT - 1)];
  irf_input[t] = acc;
  red[t] = acc;
  __syncthreads();
  for (int s = 512; s > 0; s >>= 1) {
    if (t < s) red[t] += red[t + s];
    __syncthreads();
  }
  if (t == 0) S[0] = red[0];
}

// corr_norm[k][n]: zero-mean over k (64), divide by (L2 norm + 1e-8). One wave per column.
__global__ __launch_bounds__(256) void corr_init(const float* __restrict__ cmat,
                                                 float* __restrict__ corr) {
  int lane = threadIdx.x & 63;
  int wv = threadIdx.x >> 6;
  int n = blockIdx.x * 4 + wv;
  float w = cmat[lane * NT + n];
  float s = w;
#pragma unroll
  for (int off = 32; off > 0; off >>= 1) s += __shfl_xor(s, off);
  float mean = s * (1.0f / 64.0f);
  float d = w - mean;
  float q = d * d;
#pragma unroll
  for (int off = 32; off > 0; off >>= 1) q += __shfl_xor(q, off);
  corr[lane * NT + n] = d / (sqrtf(q) + 1e-8f);
}

// Fused main kernel: per block, RB=8 batch rows.
//  Phase B: build noisy rows in LDS. Thread t owns columns {t, t+256, t+512,
//           t+768}: gather/store addresses are lane+const -> all 32 banks,
//           conflict-free, no swizzle needed. Noise loads scalar but coalesced.
//  Phase C: out[r][k] = sum_c cmat[k][c]*noisy[r][c]; 4 k-rows per thread so
//           each LDS read feeds 16 FMAs; cross-c reduce via shfl + small LDS;
//           zero-norm over k -> in_s (LDS).
//  Phase D: zncc[r][n] = sum_k in_s[r][k]*corr[k][n]; write zncc; fused
//           softmax(100*zncc) -> pred depth (zncc tile stays in registers).
__global__ __launch_bounds__(256) void fused_main(const int* __restrict__ bins,
                                                  const float* __restrict__ photon,
                                                  const float* __restrict__ sbrs,
                                                  const float* __restrict__ noise,
                                                  const float* __restrict__ cmat,
                                                  const float* __restrict__ irf_input,
                                                  const float* __restrict__ Sp,
                                                  const float* __restrict__ corr,
                                                  float* __restrict__ zncc,
                                                  float* __restrict__ pred) {
  __shared__ float irf_s[NT];
  __shared__ float noisy_s[RB][NT];
  __shared__ float part[4][64][9];   // [wave][k][r], 9-pad -> <=2-way conflicts
  __shared__ float in_s[RB][64];
  __shared__ float redm[4][RB];
  __shared__ float rede[4][RB];
  __shared__ float redn[4][RB];

  int tid = threadIdx.x;
  for (int i = tid; i < NT; i += 256) irf_s[i] = irf_input[i];
  __syncthreads();
  float S = Sp[0];
  long b0 = (long)blockIdx.x * RB;

  // ---- Phase B: noisy rows (stride-256 ownership, conflict-free LDS) ----
#pragma unroll 1
  for (int r = 0; r < RB; ++r) {
    long b = b0 + r;
    int shift = bins[b] & (NT - 1);
    float ph = photon[b];
    float scal = ph / S;
    float amb = ph / sbrs[b] * (1.0f / 1024.0f);
    const float* nrow = noise + b * NT;
#pragma unroll
    for (int m = 0; m < 4; ++m) {
      int c = tid + m * 256;
      float nz = nrow[c];
      float sc = irf_s[(c - shift) & (NT - 1)] * scal + amb;
      noisy_s[r][c] = sc + sqrtf(sc) * nz;
    }
  }
  __syncthreads();

  // ---- Phase C: GEMM1. lane = (cg[2b hi] | kg[4b lo]); wave wv owns columns
  // [wv*256, wv*256+256) split 4 ways by cg; each thread owns 4 k-rows.
  int lane = tid & 63, wv = tid >> 6;
  int kg = lane & 15, k0 = kg * 4;
  int cgw = lane >> 4;
  int cbase = (wv * 4 + cgw) * 64;
  {
    float acc[4][RB];
#pragma unroll
    for (int kk = 0; kk < 4; ++kk)
#pragma unroll
      for (int r = 0; r < RB; ++r) acc[kk][r] = 0.0f;

    const float* cm = cmat + (size_t)k0 * NT + cbase;
#pragma unroll 2
    for (int cc = 0; cc < 64; cc += 4) {
      float4 w0 = *reinterpret_cast<const float4*>(cm + 0 * NT + cc);
      float4 w1 = *reinterpret_cast<const float4*>(cm + 1 * NT + cc);
      float4 w2 = *reinterpret_cast<const float4*>(cm + 2 * NT + cc);
      float4 w3 = *reinterpret_cast<const float4*>(cm + 3 * NT + cc);
#pragma unroll
      for (int r = 0; r < RB; ++r) {
        float4 n4 = *reinterpret_cast<const float4*>(&noisy_s[r][cbase + cc]);
        acc[0][r] = fmaf(w0.w, n4.w, fmaf(w0.z, n4.z, fmaf(w0.y, n4.y, fmaf(w0.x, n4.x, acc[0][r]))));
        acc[1][r] = fmaf(w1.w, n4.w, fmaf(w1.z, n4.z, fmaf(w1.y, n4.y, fmaf(w1.x, n4.x, acc[1][r]))));
        acc[2][r] = fmaf(w2.w, n4.w, fmaf(w2.z, n4.z, fmaf(w2.y, n4.y, fmaf(w2.x, n4.x, acc[2][r]))));
        acc[3][r] = fmaf(w3.w, n4.w, fmaf(w3.z, n4.z, fmaf(w3.y, n4.y, fmaf(w3.x, n4.x, acc[3][r]))));
      }
    }
    // reduce over cg (lane bits 4,5) in-register
#pragma unroll
    for (int kk = 0; kk < 4; ++kk)
#pragma unroll
      for (int r = 0; r < RB; ++r) {
        float v = acc[kk][r];
        v += __shfl_xor(v, 16);
        v += __shfl_xor(v, 32);
        acc[kk][r] = v;
      }
    if (cgw == 0) {
#pragma unroll
      for (int kk = 0; kk < 4; ++kk)
#pragma unroll
        for (int r = 0; r < RB; ++r) part[wv][k0 + kk][r] = acc[kk][r];
    }
  }
  __syncthreads();
  // combine waves + zero-norm over k. Wave wv handles rows 2wv, 2wv+1; lane = k.
#pragma unroll
  for (int rr = 0; rr < 2; ++rr) {
    int r = wv * 2 + rr;
    float v = part[0][lane][r] + part[1][lane][r] +
              part[2][lane][r] + part[3][lane][r];
    float s = v;
#pragma unroll
    for (int off = 32; off > 0; off >>= 1) s += __shfl_xor(s, off);
    float mean = s * (1.0f / 64.0f);
    float d = v - mean;
    float q = d * d;
#pragma unroll
    for (int off = 32; off > 0; off >>= 1) q += __shfl_xor(q, off);
    in_s[r][lane] = d / (sqrtf(q) + 1e-8f);
  }
  __syncthreads();

  // ---- Phase D: GEMM2 + zncc write + fused softmax/pred ----
  int n0 = tid * 4;
  float acc[RB][4];
#pragma unroll
  for (int r = 0; r < RB; ++r)
#pragma unroll
    for (int j = 0; j < 4; ++j) acc[r][j] = 0.0f;

  for (int k4 = 0; k4 < 64; k4 += 4) {
    float4 cv0 = *reinterpret_cast<const float4*>(corr + (size_t)(k4 + 0) * NT + n0);
    float4 cv1 = *reinterpret_cast<const float4*>(corr + (size_t)(k4 + 1) * NT + n0);
    float4 cv2 = *reinterpret_cast<const float4*>(corr + (size_t)(k4 + 2) * NT + n0);
    float4 cv3 = *reinterpret_cast<const float4*>(corr + (size_t)(k4 + 3) * NT + n0);
#pragma unroll
    for (int r = 0; r < RB; ++r) {
      float4 iv = *reinterpret_cast<const float4*>(&in_s[r][k4]);
      acc[r][0] = fmaf(iv.x, cv0.x, fmaf(iv.y, cv1.x, fmaf(iv.z, cv2.x, fmaf(iv.w, cv3.x, acc[r][0]))));
      acc[r][1] = fmaf(iv.x, cv0.y, fmaf(iv.y, cv1.y, fmaf(iv.z, cv2.y, fmaf(iv.w, cv3.y, acc[r][1]))));
      acc[r][2] = fmaf(iv.x, cv0.z, fmaf(iv.y, cv1.z, fmaf(iv.z, cv2.z, fmaf(iv.w, cv3.z, acc[r][2]))));
      acc[r][3] = fmaf(iv.x, cv0.w, fmaf(iv.y, cv1.w, fmaf(iv.z, cv2.w, fmaf(iv.w, cv3.w, acc[r][3]))));
    }
  }

#pragma unroll
  for (int r = 0; r < RB; ++r) {
    float4 z;
    z.x = acc[r][0]; z.y = acc[r][1]; z.z = acc[r][2]; z.w = acc[r][3];
    *reinterpret_cast<float4*>(zncc + (b0 + r) * NT + n0) = z;
  }

  // per-row max
#pragma unroll
  for (int r = 0; r < RB; ++r) {
    float m = fmaxf(fmaxf(acc[r][0], acc[r][1]), fmaxf(acc[r][2], acc[r][3]));
#pragma unroll
    for (int off = 32; off > 0; off >>= 1) m = fmaxf(m, __shfl_xor(m, off));
    if (lane == 0) redm[wv][r] = m;
  }
  __syncthreads();
  float rmax[RB];
#pragma unroll
  for (int r = 0; r < RB; ++r)
    rmax[r] = fmaxf(fmaxf(redm[0][r], redm[1][r]), fmaxf(redm[2][r], redm[3][r]));
  // exp sums + index-weighted sums
#pragma unroll
  for (int r = 0; r < RB; ++r) {
    float e0 = expf(100.0f * (acc[r][0] - rmax[r]));
    float e1 = expf(100.0f * (acc[r][1] - rmax[r]));
    float e2 = expf(100.0f * (acc[r][2] - rmax[r]));
    float e3 = expf(100.0f * (acc[r][3] - rmax[r]));
    float es = e0 + e1 + e2 + e3;
    float ns = e0 * (float)(n0 + 0) + e1 * (float)(n0 + 1) +
               e2 * (float)(n0 + 2) + e3 * (float)(n0 + 3);
#pragma unroll
    for (int off = 32; off > 0; off >>= 1) {
      es += __shfl_xor(es, off);
      ns += __shfl_xor(ns, off);
    }
    if (lane == 0) { rede[wv][r] = es; redn[wv][r] = ns; }
  }
  __syncthreads();
  if (tid < RB) {
    int r = tid;
    float es = rede[0][r] + rede[1][r] + rede[2][r] + rede[3][r];
    float ns = redn[0][r] + redn[1][r] + redn[2][r] + redn[3][r];
    pred[b0 + r] = ns / es;
  }
}

extern "C" void kernel_launch(void* const* d_in, const int* in_sizes, int n_in,
                              void* d_out, int out_size, void* d_ws, size_t ws_size,
                              hipStream_t stream) {
  const int*   bins   = (const int*)d_in[0];
  const float* photon = (const float*)d_in[1];
  const float* sbrs   = (const float*)d_in[2];
  const float* learn  = (const float*)d_in[3];
  const float* cmat   = (const float*)d_in[4];
  const float* noise  = (const float*)d_in[5];
  float* out = (float*)d_out;
  float* ws = (float*)d_ws;

  float* irf_input  = ws + 2048;        // 1024
  float* Sslot      = ws + 3072;        // 1
  float* corr       = ws + 4096;        // 64*1024

  int B = in_sizes[0];
  float* pred = out + (size_t)B * NT;

  hipLaunchKernelGGL(prelude, dim3(1), dim3(1024), 0, stream, learn, irf_input, Sslot);
  hipLaunchKernelGGL(corr_init, dim3(256), dim3(256), 0, stream, cmat, corr);
  hipLaunchKernelGGL(fused_main, dim3(B / RB), dim3(256), 0, stream,
                     bins, photon, sbrs, noise, cmat, irf_input, Sslot, corr, out, pred);
}

// Round 5
// 210.626 us; speedup vs baseline: 1.1495x; 1.1333x over previous
//
#include <hip/hip_runtime.h>
#include <math.h>

// IlluminationModel, MFMA split-bf16 pipeline for MI355X (gfx950).
// B=16384, N=1024, K=64. Output: zncc (B*N) then pred_depths (B), f32.
//
// GEMMs run as bf16 hi/lo split (v = hi + lo) on mfma_f32_16x16x32_bf16:
//   A*B = Ah*Bh + Ah*Bl + Al*Bh  (error ~2^-18 relative, ~f32-equivalent).
//
// ws layout:
//   f32  irf_input[1024], S[1]
//   u16  cmatH[64*1024], cmatL[64*1024]        (cmat bf16 planes, row-major [k][c])
//   u16  corrTH[1024*64], corrTL[1024*64]      (corr_norm TRANSPOSED [n][k] planes)

#define NT 1024

typedef unsigned short u16;
typedef short bf16x8 __attribute__((ext_vector_type(8)));
typedef float f32x4 __attribute__((ext_vector_type(4)));

__device__ __forceinline__ u16 f2bf(float f) {          // round-to-nearest-even
  unsigned u = __float_as_uint(f);
  u = u + 0x7FFFu + ((u >> 16) & 1u);
  return (u16)(u >> 16);
}
__device__ __forceinline__ float bf2f(u16 h) {
  return __uint_as_float(((unsigned)h) << 16);
}

// Single-block prelude: gaussian IRF -> normalize/roll -> relu(x) -> circular
// conv (support |d|<=96; dropped terms < e^-46) -> sum S; cmat bf16 planes.
__global__ __launch_bounds__(1024) void prelude(const float* __restrict__ learn,
                                                const float* __restrict__ cmat,
                                                float* __restrict__ irf_input,
                                                float* __restrict__ S,
                                                u16* __restrict__ cmatH,
                                                u16* __restrict__ cmatL) {
  __shared__ float red[NT];
  __shared__ float irf_l[NT];
  __shared__ float x_l[NT];
  int t = threadIdx.x;
  float d = ((float)t - 511.0f) / 10.0f;               // mu=511, sigma=10
  float g = expf(-0.5f * d * d);
  red[t] = g;
  __syncthreads();
  for (int s = 512; s > 0; s >>= 1) {
    if (t < s) red[t] += red[t + s];
    __syncthreads();
  }
  float gsum = red[0];
  irf_l[(t - 511) & (NT - 1)] = g / gsum;              // roll by -mu
  x_l[t] = fmaxf(learn[t], 0.0f);
  __syncthreads();
  float acc = 0.0f;
  for (int dd = -96; dd <= 96; ++dd)
    acc += irf_l[dd & (NT - 1)] * x_l[(t - dd) & (NT - 1)];
  irf_input[t] = acc;
  red[t] = acc;
  __syncthreads();
  for (int s = 512; s > 0; s >>= 1) {
    if (t < s) red[t] += red[t + s];
    __syncthreads();
  }
  if (t == 0) S[0] = red[0];
  // cmat -> bf16 hi/lo planes (same [k][c] layout), coalesced
  for (int j = 0; j < 64; ++j) {
    int idx = t + NT * j;
    float v = cmat[idx];
    u16 h = f2bf(v);
    cmatH[idx] = h;
    cmatL[idx] = f2bf(v - bf2f(h));
  }
}

// corr_norm[k][n] = zero-mean/L2-norm over k; stored TRANSPOSED [n][k] bf16 hi/lo.
__global__ __launch_bounds__(256) void corr_init(const float* __restrict__ cmat,
                                                 u16* __restrict__ corrTH,
                                                 u16* __restrict__ corrTL) {
  int lane = threadIdx.x & 63;
  int wv = threadIdx.x >> 6;
  int n = blockIdx.x * 4 + wv;
  float w = cmat[lane * NT + n];
  float s = w;
#pragma unroll
  for (int off = 32; off > 0; off >>= 1) s += __shfl_xor(s, off);
  float mean = s * (1.0f / 64.0f);
  float dd = w - mean;
  float q = dd * dd;
#pragma unroll
  for (int off = 32; off > 0; off >>= 1) q += __shfl_xor(q, off);
  float val = dd / (sqrtf(q) + 1e-8f);
  u16 h = f2bf(val);
  corrTH[n * 64 + lane] = h;
  corrTL[n * 64 + lane] = f2bf(val - bf2f(h));
}

// Fused main: 16 batch rows per block, 4 waves (256 thr).
//  A) build noisy rows as bf16 hi/lo LDS planes (XOR-swizzled rows).
//  B) GEMM1 via MFMA: out[16r][64k] = noisy . cmat^T; zero-norm over k -> inorm LDS.
//  C) GEMM2 via MFMA: zncc[16r][1024n] = inorm . corrT^T; store zncc; fused
//     softmax(100*zncc) -> pred (zncc tile register-resident).
__global__ __launch_bounds__(256, 2) void fused_main(const int* __restrict__ bins,
                                                     const float* __restrict__ photon,
                                                     const float* __restrict__ sbrs,
                                                     const float* __restrict__ noise,
                                                     const float* __restrict__ irfin,
                                                     const float* __restrict__ Sp,
                                                     const u16* __restrict__ cmatH,
                                                     const u16* __restrict__ cmatL,
                                                     const u16* __restrict__ corrTH,
                                                     const u16* __restrict__ corrTL,
                                                     float* __restrict__ zncc,
                                                     float* __restrict__ pred) {
  __shared__ float irf_s[NT];                      // 4KB
  __shared__ u16 noisyH[16 * NT];                  // 32KB, swizzled byte^((r&7)<<4)
  __shared__ u16 noisyL[16 * NT];                  // 32KB
  __shared__ float out_s[16][68];                  // GEMM1 result, padded
  __shared__ u16 inormH[16 * 64];                  // 2KB, swizzled
  __shared__ u16 inormL[16 * 64];                  // 2KB
  __shared__ float red_m[4][16];
  __shared__ float red_e[4][16];
  __shared__ float red_n[4][16];

  int tid = threadIdx.x;
  int lane = tid & 63, w = tid >> 6;
  int row = lane & 15, kg = lane >> 4;             // MFMA fragment coords
  long b0 = (long)blockIdx.x * 16;

  for (int i = tid; i < NT; i += 256) irf_s[i] = irfin[i];
  __syncthreads();
  float S = Sp[0];

  // ---- Phase A: noisy -> bf16 hi/lo planes. Wave w owns rows 4w..4w+3;
  // lane handles c = 2*lane + 128*i (stride-1 word LDS writes, conflict-free).
#pragma unroll 1
  for (int rr = 0; rr < 4; ++rr) {
    int r = w * 4 + rr;
    long b = b0 + r;
    int shift = bins[b] & (NT - 1);
    float ph = photon[b];
    float scal = ph / S;
    float amb = ph / sbrs[b] * (1.0f / 1024.0f);
    const float* nrow = noise + b * NT;
#pragma unroll
    for (int i = 0; i < 8; ++i) {
      int c0 = 2 * lane + 128 * i;
      float2 nz = *reinterpret_cast<const float2*>(nrow + c0);
      float sc0 = fmaf(irf_s[(c0 - shift) & (NT - 1)], scal, amb);
      float sc1 = fmaf(irf_s[(c0 + 1 - shift) & (NT - 1)], scal, amb);
      float v0 = fmaf(sqrtf(sc0), nz.x, sc0);
      float v1 = fmaf(sqrtf(sc1), nz.y, sc1);
      u16 h0 = f2bf(v0), h1 = f2bf(v1);
      u16 l0 = f2bf(v0 - bf2f(h0)), l1 = f2bf(v1 - bf2f(h1));
      int word = (r * 512 + lane + 64 * i) ^ ((r & 7) << 2);
      reinterpret_cast<unsigned*>(noisyH)[word] = (unsigned)h0 | ((unsigned)h1 << 16);
      reinterpret_cast<unsigned*>(noisyL)[word] = (unsigned)l0 | ((unsigned)l1 << 16);
    }
  }
  __syncthreads();

  // ---- Phase B: GEMM1. Wave w -> output k-tile [16w,16w+16). A-frag: lane reads
  // noisy[row][c0+8kg .. +8] (swizzled LDS); B-frag: cmat[16w+row][c0+8kg .. +8] (global).
  {
    const u16* cHp = cmatH + (size_t)(16 * w + row) * NT + 8 * kg;
    const u16* cLp = cmatL + (size_t)(16 * w + row) * NT + 8 * kg;
    int aBase = row * 2048 + 16 * kg;
    int swz = (row & 7) << 4;
    f32x4 aHH = {0.f, 0.f, 0.f, 0.f}, aHL = aHH, aLH = aHH;
#pragma unroll 4
    for (int s = 0; s < 32; ++s) {
      int off = (aBase + 64 * s) ^ swz;
      bf16x8 ah = *reinterpret_cast<const bf16x8*>(reinterpret_cast<const char*>(noisyH) + off);
      bf16x8 al = *reinterpret_cast<const bf16x8*>(reinterpret_cast<const char*>(noisyL) + off);
      bf16x8 bh = *reinterpret_cast<const bf16x8*>(cHp + 32 * s);
      bf16x8 bl = *reinterpret_cast<const bf16x8*>(cLp + 32 * s);
      aHH = __builtin_amdgcn_mfma_f32_16x16x32_bf16(ah, bh, aHH, 0, 0, 0);
      aHL = __builtin_amdgcn_mfma_f32_16x16x32_bf16(ah, bl, aHL, 0, 0, 0);
      aLH = __builtin_amdgcn_mfma_f32_16x16x32_bf16(al, bh, aLH, 0, 0, 0);
    }
    f32x4 o = aHH + aHL + aLH;
#pragma unroll
    for (int q = 0; q < 4; ++q) out_s[4 * kg + q][16 * w + row] = o[q];
  }
  __syncthreads();

  // ---- zero-norm over k (64) -> inorm bf16 planes. Wave w: rows 4w..4w+3.
#pragma unroll
  for (int rr = 0; rr < 4; ++rr) {
    int r = w * 4 + rr;
    float v = out_s[r][lane];
    float s = v;
#pragma unroll
    for (int off = 32; off > 0; off >>= 1) s += __shfl_xor(s, off);
    float mean = s * (1.0f / 64.0f);
    float dd = v - mean;
    float q = dd * dd;
#pragma unroll
    for (int off = 32; off > 0; off >>= 1) q += __shfl_xor(q, off);
    float val = dd / (sqrtf(q) + 1e-8f);
    u16 h = f2bf(val);
    u16 lo = f2bf(val - bf2f(h));
    int boff = (r * 128 + lane * 2) ^ ((r & 7) << 4);
    *reinterpret_cast<u16*>(reinterpret_cast<char*>(inormH) + boff) = h;
    *reinterpret_cast<u16*>(reinterpret_cast<char*>(inormL) + boff) = lo;
  }
  __syncthreads();

  // ---- Phase C: GEMM2. Wave w owns n in [256w, 256w+256), 16 tiles of 16.
  // A-frags (inorm) hoisted once; B-frags from corrT planes (global).
  int swz = (row & 7) << 4;
  int a0 = (row * 128 + 16 * kg) ^ swz;            // kc = 0
  int a1 = (row * 128 + 64 + 16 * kg) ^ swz;       // kc = 32
  bf16x8 a2h0 = *reinterpret_cast<const bf16x8*>(reinterpret_cast<const char*>(inormH) + a0);
  bf16x8 a2h1 = *reinterpret_cast<const bf16x8*>(reinterpret_cast<const char*>(inormH) + a1);
  bf16x8 a2l0 = *reinterpret_cast<const bf16x8*>(reinterpret_cast<const char*>(inormL) + a0);
  bf16x8 a2l1 = *reinterpret_cast<const bf16x8*>(reinterpret_cast<const char*>(inormL) + a1);

  f32x4 acc2[16];
  f32x4 mx = {-INFINITY, -INFINITY, -INFINITY, -INFINITY};
#pragma unroll
  for (int j = 0; j < 16; ++j) {
    int n0 = 256 * w + 16 * j;
    const u16* pH = corrTH + (size_t)(n0 + row) * 64 + 8 * kg;
    const u16* pL = corrTL + (size_t)(n0 + row) * 64 + 8 * kg;
    bf16x8 b0h = *reinterpret_cast<const bf16x8*>(pH);
    bf16x8 b1h = *reinterpret_cast<const bf16x8*>(pH + 32);
    bf16x8 b0l = *reinterpret_cast<const bf16x8*>(pL);
    bf16x8 b1l = *reinterpret_cast<const bf16x8*>(pL + 32);
    f32x4 t1 = {0.f, 0.f, 0.f, 0.f}, t2 = t1, t3 = t1;
    t1 = __builtin_amdgcn_mfma_f32_16x16x32_bf16(a2h0, b0h, t1, 0, 0, 0);
    t2 = __builtin_amdgcn_mfma_f32_16x16x32_bf16(a2h0, b0l, t2, 0, 0, 0);
    t3 = __builtin_amdgcn_mfma_f32_16x16x32_bf16(a2l0, b0h, t3, 0, 0, 0);
    t1 = __builtin_amdgcn_mfma_f32_16x16x32_bf16(a2h1, b1h, t1, 0, 0, 0);
    t2 = __builtin_amdgcn_mfma_f32_16x16x32_bf16(a2h1, b1l, t2, 0, 0, 0);
    t3 = __builtin_amdgcn_mfma_f32_16x16x32_bf16(a2l1, b1h, t3, 0, 0, 0);
    f32x4 z = t1 + t2 + t3;
    acc2[j] = z;
#pragma unroll
    for (int q = 0; q < 4; ++q) {
      zncc[(b0 + 4 * kg + q) * NT + n0 + row] = z[q];
      mx[q] = fmaxf(mx[q], z[q]);
    }
  }

  // row-max: reduce within 16-lane group, then across waves via LDS
#pragma unroll
  for (int q = 0; q < 4; ++q) {
#pragma unroll
    for (int off = 1; off < 16; off <<= 1) mx[q] = fmaxf(mx[q], __shfl_xor(mx[q], off));
  }
  if (row == 0) {
#pragma unroll
    for (int q = 0; q < 4; ++q) red_m[w][4 * kg + q] = mx[q];
  }
  __syncthreads();
  f32x4 rm;
#pragma unroll
  for (int q = 0; q < 4; ++q)
    rm[q] = fmaxf(fmaxf(red_m[0][4 * kg + q], red_m[1][4 * kg + q]),
                  fmaxf(red_m[2][4 * kg + q], red_m[3][4 * kg + q]));

  // exp pass over register-resident zncc tile
  f32x4 es = {0.f, 0.f, 0.f, 0.f}, ns = es;
#pragma unroll
  for (int j = 0; j < 16; ++j) {
    float nf = (float)(256 * w + 16 * j + row);
#pragma unroll
    for (int q = 0; q < 4; ++q) {
      float e = expf(100.0f * (acc2[j][q] - rm[q]));
      es[q] += e;
      ns[q] = fmaf(nf, e, ns[q]);
    }
  }
#pragma unroll
  for (int q = 0; q < 4; ++q) {
#pragma unroll
    for (int off = 1; off < 16; off <<= 1) {
      es[q] += __shfl_xor(es[q], off);
      ns[q] += __shfl_xor(ns[q], off);
    }
  }
  if (row == 0) {
#pragma unroll
    for (int q = 0; q < 4; ++q) { red_e[w][4 * kg + q] = es[q]; red_n[w][4 * kg + q] = ns[q]; }
  }
  __syncthreads();
  if (tid < 16) {
    float e = red_e[0][tid] + red_e[1][tid] + red_e[2][tid] + red_e[3][tid];
    float n = red_n[0][tid] + red_n[1][tid] + red_n[2][tid] + red_n[3][tid];
    pred[b0 + tid] = n / e;
  }
}

extern "C" void kernel_launch(void* const* d_in, const int* in_sizes, int n_in,
                              void* d_out, int out_size, void* d_ws, size_t ws_size,
                              hipStream_t stream) {
  const int*   bins   = (const int*)d_in[0];
  const float* photon = (const float*)d_in[1];
  const float* sbrs   = (const float*)d_in[2];
  const float* learn  = (const float*)d_in[3];
  const float* cmat   = (const float*)d_in[4];
  const float* noise  = (const float*)d_in[5];
  float* out = (float*)d_out;
  float* wsf = (float*)d_ws;

  float* irf_input = wsf;                  // 1024 f32
  float* Sslot     = wsf + 1024;           // 1 f32
  u16* cmatH  = (u16*)(wsf + 2048);        // 65536 u16
  u16* cmatL  = cmatH + 65536;
  u16* corrTH = cmatL + 65536;             // [n][k] transposed planes
  u16* corrTL = corrTH + 65536;

  int B = in_sizes[0];
  float* pred = out + (size_t)B * NT;

  hipLaunchKernelGGL(prelude, dim3(1), dim3(1024), 0, stream,
                     learn, cmat, irf_input, Sslot, cmatH, cmatL);
  hipLaunchKernelGGL(corr_init, dim3(256), dim3(256), 0, stream, cmat, corrTH, corrTL);
  hipLaunchKernelGGL(fused_main, dim3(B / 16), dim3(256), 0, stream,
                     bins, photon, sbrs, noise, irf_input, Sslot,
                     cmatH, cmatL, corrTH, corrTL, out, pred);
}

// Round 6
// 190.217 us; speedup vs baseline: 1.2728x; 1.1073x over previous
//
#include <hip/hip_runtime.h>
#include <math.h>

// IlluminationModel, MFMA split-bf16 pipeline for MI355X (gfx950), round 6.
// B=16384, N=1024, K=64. Output: zncc (B*N) then pred_depths (B), f32.
//
// GEMMs run as bf16 hi/lo split (v = hi + lo) on mfma_f32_16x16x32_bf16:
//   A*B = Ah*Bh + Ah*Bl + Al*Bh  (error ~2^-18 relative, ~f32-equivalent),
// all three terms chained into one accumulator via MFMA C-in.
//
// Round-6 structure change: GEMM1 is split by c-quarter per wave; noisy
// fragments are generated in REGISTERS (no 64KB LDS staging), partial sums
// reduced cross-wave through a 17KB f32 LDS buffer. LDS 77KB -> 26KB, so
// __launch_bounds__(256,4) gives 4 blocks/CU = 16 waves/CU (was 8), and
// grid = 1024 blocks = exactly 4/CU x 256 CU (fully resident).
//
// ws layout:
//   f32  irf_input[1024], S[1]   at wsf[0..1025)
//   u16  cmatH[64*1024], cmatL[64*1024]        ([k][c] bf16 planes)
//   u16  corrTH[1024*64], corrTL[1024*64]      (corr_norm TRANSPOSED [n][k])

#define NT 1024

typedef unsigned short u16;
typedef short bf16x8 __attribute__((ext_vector_type(8)));
typedef float f32x4 __attribute__((ext_vector_type(4)));

__device__ __forceinline__ u16 f2bf(float f) {          // round-to-nearest-even
  unsigned u = __float_as_uint(f);
  u = u + 0x7FFFu + ((u >> 16) & 1u);
  return (u16)(u >> 16);
}
__device__ __forceinline__ float bf2f(u16 h) {
  return __uint_as_float(((unsigned)h) << 16);
}

// Single-block prelude (irf chain only): gaussian IRF -> normalize/roll ->
// relu(x) -> circular conv (|d|<=96; dropped terms < e^-46) -> sum S.
__global__ __launch_bounds__(1024) void prelude(const float* __restrict__ learn,
                                                float* __restrict__ irf_input,
                                                float* __restrict__ S) {
  __shared__ float red[NT];
  __shared__ float irf_l[NT];
  __shared__ float x_l[NT];
  int t = threadIdx.x;
  float d = ((float)t - 511.0f) / 10.0f;               // mu=511, sigma=10
  float g = expf(-0.5f * d * d);
  red[t] = g;
  __syncthreads();
  for (int s = 512; s > 0; s >>= 1) {
    if (t < s) red[t] += red[t + s];
    __syncthreads();
  }
  float gsum = red[0];
  irf_l[(t - 511) & (NT - 1)] = g / gsum;              // roll by -mu
  x_l[t] = fmaxf(learn[t], 0.0f);
  __syncthreads();
  float acc = 0.0f;
  for (int dd = -96; dd <= 96; ++dd)
    acc += irf_l[dd & (NT - 1)] * x_l[(t - dd) & (NT - 1)];
  irf_input[t] = acc;
  red[t] = acc;
  __syncthreads();
  for (int s = 512; s > 0; s >>= 1) {
    if (t < s) red[t] += red[t + s];
    __syncthreads();
  }
  if (t == 0) S[0] = red[0];
}

// corr_init: corr_norm (zero-mean/L2 over k, stored transposed [n][k] bf16
// planes) + cmat -> bf16 hi/lo plane conversion (moved out of prelude).
__global__ __launch_bounds__(256) void corr_init(const float* __restrict__ cmat,
                                                 u16* __restrict__ corrTH,
                                                 u16* __restrict__ corrTL,
                                                 u16* __restrict__ cmatH,
                                                 u16* __restrict__ cmatL) {
  int tid = threadIdx.x;
  // cmat plane conversion: 256 blocks x 256 thr = 65536 elems, coalesced
  {
    int idx = blockIdx.x * 256 + tid;
    float v = cmat[idx];
    u16 h = f2bf(v);
    cmatH[idx] = h;
    cmatL[idx] = f2bf(v - bf2f(h));
  }
  int lane = tid & 63;
  int wv = tid >> 6;
  int n = blockIdx.x * 4 + wv;
  float w = cmat[lane * NT + n];
  float s = w;
#pragma unroll
  for (int off = 32; off > 0; off >>= 1) s += __shfl_xor(s, off);
  float mean = s * (1.0f / 64.0f);
  float dd = w - mean;
  float q = dd * dd;
#pragma unroll
  for (int off = 32; off > 0; off >>= 1) q += __shfl_xor(q, off);
  float val = dd / (sqrtf(q) + 1e-8f);
  u16 h = f2bf(val);
  corrTH[n * 64 + lane] = h;
  corrTL[n * 64 + lane] = f2bf(val - bf2f(h));
}

// Fused main: 16 batch rows per block, 4 waves.
//  1) GEMM1 fused with generation: wave w owns c in [256w,256w+256); per
//     32-col slice each lane builds its noisy hi/lo a-frag in registers and
//     chains 3 MFMAs into each of the 4 k-tile accumulators.
//  2) cross-wave reduce (f32 LDS) + zero-norm over k -> inorm bf16 planes.
//  3) GEMM2: zncc = inorm . corrT^T; store zncc; fused softmax -> pred.
__global__ __launch_bounds__(256, 4) void fused_main(const int* __restrict__ bins,
                                                     const float* __restrict__ photon,
                                                     const float* __restrict__ sbrs,
                                                     const float* __restrict__ noise,
                                                     const float* __restrict__ irfin,
                                                     const float* __restrict__ Sp,
                                                     const u16* __restrict__ cmatH,
                                                     const u16* __restrict__ cmatL,
                                                     const u16* __restrict__ corrTH,
                                                     const u16* __restrict__ corrTL,
                                                     float* __restrict__ zncc,
                                                     float* __restrict__ pred) {
  __shared__ float irf_s[NT];                      // 4KB
  __shared__ float part[4][16][68];                // 17.4KB [wave][batch r][k], padded
  __shared__ u16 inormH[16 * 64];                  // 2KB, swizzled
  __shared__ u16 inormL[16 * 64];                  // 2KB
  __shared__ float red_m[4][16];
  __shared__ float red_e[4][16];
  __shared__ float red_n[4][16];

  int tid = threadIdx.x;
  int lane = tid & 63, w = tid >> 6;
  int row = lane & 15, kg = lane >> 4;             // MFMA fragment coords
  long b0 = (long)blockIdx.x * 16;
  long b = b0 + row;

  // per-lane row params (issue before irf_s barrier to hide latency)
  int shift = bins[b] & (NT - 1);
  float ph = photon[b];
  float sb = sbrs[b];

  for (int i = tid; i < NT; i += 256) irf_s[i] = irfin[i];
  __syncthreads();
  float S = Sp[0];
  float scal = ph / S;
  float amb = ph / sb * (1.0f / 1024.0f);
  const float* nrow = noise + b * NT + w * 256;

  // ---- GEMM1 + generation fused ----
  f32x4 acc[4];
#pragma unroll
  for (int t = 0; t < 4; ++t) acc[t] = (f32x4){0.f, 0.f, 0.f, 0.f};

#pragma unroll 2
  for (int s = 0; s < 8; ++s) {
    int c = 8 * kg + 32 * s;                       // local col in this wave's quarter
    int cabs = w * 256 + c;                        // absolute col
    float4 nz0 = *reinterpret_cast<const float4*>(nrow + c);
    float4 nz1 = *reinterpret_cast<const float4*>(nrow + c + 4);
    float nzv[8] = {nz0.x, nz0.y, nz0.z, nz0.w, nz1.x, nz1.y, nz1.z, nz1.w};
    bf16x8 ah, al;
#pragma unroll
    for (int e = 0; e < 8; ++e) {
      float sc = fmaf(irf_s[(cabs + e - shift) & (NT - 1)], scal, amb);
      float v = fmaf(sqrtf(sc), nzv[e], sc);
      u16 h = f2bf(v);
      ah[e] = (short)h;
      al[e] = (short)f2bf(v - bf2f(h));
    }
#pragma unroll
    for (int t = 0; t < 4; ++t) {
      const u16* pH = cmatH + (size_t)(16 * t + row) * NT + cabs;
      const u16* pL = cmatL + (size_t)(16 * t + row) * NT + cabs;
      bf16x8 bh = *reinterpret_cast<const bf16x8*>(pH);
      bf16x8 bl = *reinterpret_cast<const bf16x8*>(pL);
      acc[t] = __builtin_amdgcn_mfma_f32_16x16x32_bf16(al, bh, acc[t], 0, 0, 0);
      acc[t] = __builtin_amdgcn_mfma_f32_16x16x32_bf16(ah, bl, acc[t], 0, 0, 0);
      acc[t] = __builtin_amdgcn_mfma_f32_16x16x32_bf16(ah, bh, acc[t], 0, 0, 0);
    }
  }
  // partial out: D rows m = batch 4kg+q, cols = k_out 16t+row
#pragma unroll
  for (int t = 0; t < 4; ++t)
#pragma unroll
    for (int q = 0; q < 4; ++q) part[w][4 * kg + q][16 * t + row] = acc[t][q];
  __syncthreads();

  // ---- cross-wave reduce + zero-norm over k -> inorm planes ----
#pragma unroll
  for (int rr = 0; rr < 4; ++rr) {
    int r = w * 4 + rr;
    float v = part[0][r][lane] + part[1][r][lane] +
              part[2][r][lane] + part[3][r][lane];
    float s = v;
#pragma unroll
    for (int off = 32; off > 0; off >>= 1) s += __shfl_xor(s, off);
    float mean = s * (1.0f / 64.0f);
    float dd = v - mean;
    float q = dd * dd;
#pragma unroll
    for (int off = 32; off > 0; off >>= 1) q += __shfl_xor(q, off);
    float val = dd / (sqrtf(q) + 1e-8f);
    u16 h = f2bf(val);
    u16 lo = f2bf(val - bf2f(h));
    int boff = (r * 128 + lane * 2) ^ ((r & 7) << 4);
    *reinterpret_cast<u16*>(reinterpret_cast<char*>(inormH) + boff) = h;
    *reinterpret_cast<u16*>(reinterpret_cast<char*>(inormL) + boff) = lo;
  }
  __syncthreads();

  // ---- GEMM2: wave w owns n in [256w, 256w+256), 16 tiles of 16 ----
  int swz = (row & 7) << 4;
  int a0 = (row * 128 + 16 * kg) ^ swz;            // kc = 0
  int a1 = (row * 128 + 64 + 16 * kg) ^ swz;       // kc = 32
  bf16x8 a2h0 = *reinterpret_cast<const bf16x8*>(reinterpret_cast<const char*>(inormH) + a0);
  bf16x8 a2h1 = *reinterpret_cast<const bf16x8*>(reinterpret_cast<const char*>(inormH) + a1);
  bf16x8 a2l0 = *reinterpret_cast<const bf16x8*>(reinterpret_cast<const char*>(inormL) + a0);
  bf16x8 a2l1 = *reinterpret_cast<const bf16x8*>(reinterpret_cast<const char*>(inormL) + a1);

  f32x4 acc2[16];
  f32x4 mx = {-INFINITY, -INFINITY, -INFINITY, -INFINITY};
#pragma unroll
  for (int j = 0; j < 16; ++j) {
    int n0 = 256 * w + 16 * j;
    const u16* pH = corrTH + (size_t)(n0 + row) * 64 + 8 * kg;
    const u16* pL = corrTL + (size_t)(n0 + row) * 64 + 8 * kg;
    bf16x8 b0h = *reinterpret_cast<const bf16x8*>(pH);
    bf16x8 b1h = *reinterpret_cast<const bf16x8*>(pH + 32);
    bf16x8 b0l = *reinterpret_cast<const bf16x8*>(pL);
    bf16x8 b1l = *reinterpret_cast<const bf16x8*>(pL + 32);
    f32x4 z = {0.f, 0.f, 0.f, 0.f};
    z = __builtin_amdgcn_mfma_f32_16x16x32_bf16(a2l0, b0h, z, 0, 0, 0);
    z = __builtin_amdgcn_mfma_f32_16x16x32_bf16(a2h0, b0l, z, 0, 0, 0);
    z = __builtin_amdgcn_mfma_f32_16x16x32_bf16(a2h0, b0h, z, 0, 0, 0);
    z = __builtin_amdgcn_mfma_f32_16x16x32_bf16(a2l1, b1h, z, 0, 0, 0);
    z = __builtin_amdgcn_mfma_f32_16x16x32_bf16(a2h1, b1l, z, 0, 0, 0);
    z = __builtin_amdgcn_mfma_f32_16x16x32_bf16(a2h1, b1h, z, 0, 0, 0);
    acc2[j] = z;
#pragma unroll
    for (int q = 0; q < 4; ++q) {
      zncc[(b0 + 4 * kg + q) * NT + n0 + row] = z[q];
      mx[q] = fmaxf(mx[q], z[q]);
    }
  }

  // row-max: reduce within 16-lane group (n within tile), then across waves
#pragma unroll
  for (int q = 0; q < 4; ++q) {
#pragma unroll
    for (int off = 1; off < 16; off <<= 1) mx[q] = fmaxf(mx[q], __shfl_xor(mx[q], off));
  }
  if (row == 0) {
#pragma unroll
    for (int q = 0; q < 4; ++q) red_m[w][4 * kg + q] = mx[q];
  }
  __syncthreads();
  f32x4 rm;
#pragma unroll
  for (int q = 0; q < 4; ++q)
    rm[q] = fmaxf(fmaxf(red_m[0][4 * kg + q], red_m[1][4 * kg + q]),
                  fmaxf(red_m[2][4 * kg + q], red_m[3][4 * kg + q]));

  // exp pass over register-resident zncc tile
  f32x4 es = {0.f, 0.f, 0.f, 0.f}, ns = es;
#pragma unroll
  for (int j = 0; j < 16; ++j) {
    float nf = (float)(256 * w + 16 * j + row);
#pragma unroll
    for (int q = 0; q < 4; ++q) {
      float e = __expf(100.0f * (acc2[j][q] - rm[q]));
      es[q] += e;
      ns[q] = fmaf(nf, e, ns[q]);
    }
  }
#pragma unroll
  for (int q = 0; q < 4; ++q) {
#pragma unroll
    for (int off = 1; off < 16; off <<= 1) {
      es[q] += __shfl_xor(es[q], off);
      ns[q] += __shfl_xor(ns[q], off);
    }
  }
  if (row == 0) {
#pragma unroll
    for (int q = 0; q < 4; ++q) { red_e[w][4 * kg + q] = es[q]; red_n[w][4 * kg + q] = ns[q]; }
  }
  __syncthreads();
  if (tid < 16) {
    float e = red_e[0][tid] + red_e[1][tid] + red_e[2][tid] + red_e[3][tid];
    float n = red_n[0][tid] + red_n[1][tid] + red_n[2][tid] + red_n[3][tid];
    pred[b0 + tid] = n / e;
  }
}

extern "C" void kernel_launch(void* const* d_in, const int* in_sizes, int n_in,
                              void* d_out, int out_size, void* d_ws, size_t ws_size,
                              hipStream_t stream) {
  const int*   bins   = (const int*)d_in[0];
  const float* photon = (const float*)d_in[1];
  const float* sbrs   = (const float*)d_in[2];
  const float* learn  = (const float*)d_in[3];
  const float* cmat   = (const float*)d_in[4];
  const float* noise  = (const float*)d_in[5];
  float* out = (float*)d_out;
  float* wsf = (float*)d_ws;

  float* irf_input = wsf;                  // 1024 f32
  float* Sslot     = wsf + 1024;           // 1 f32
  u16* cmatH  = (u16*)(wsf + 2048);        // 65536 u16
  u16* cmatL  = cmatH + 65536;
  u16* corrTH = cmatL + 65536;             // [n][k] transposed planes
  u16* corrTL = corrTH + 65536;

  int B = in_sizes[0];
  float* pred = out + (size_t)B * NT;

  hipLaunchKernelGGL(prelude, dim3(1), dim3(1024), 0, stream, learn, irf_input, Sslot);
  hipLaunchKernelGGL(corr_init, dim3(256), dim3(256), 0, stream,
                     cmat, corrTH, corrTL, cmatH, cmatL);
  hipLaunchKernelGGL(fused_main, dim3(B / 16), dim3(256), 0, stream,
                     bins, photon, sbrs, noise, irf_input, Sslot,
                     cmatH, cmatL, corrTH, corrTL, out, pred);
}